// Round 1
// baseline (2530.650 us; speedup 1.0000x reference)
//
#include <hip/hip_runtime.h>

#define NROWS 65536
#define DDIM 768
#define KCODES 128
#define LLAYERS 8
#define F4D 192  // 768/4

// ws layout: bytes [0,64): double Rsum[8]; [64,128): double minsum[8]; [128,...): float n2[1024]

__global__ __launch_bounds__(64)
void k_norms(const float* __restrict__ cb, float* __restrict__ n2) {
    int c = blockIdx.x;  // 0..1023 = l*128+code
    const float* p = cb + (size_t)c * DDIM;
    int lane = threadIdx.x;
    float s = 0.f;
    for (int k = lane; k < DDIM; k += 64) s = fmaf(p[k], p[k], s);
    for (int off = 32; off > 0; off >>= 1) s += __shfl_down(s, off);
    if (lane == 0) n2[c] = s;
}

__global__ __launch_bounds__(256)
void k_layer(const float* __restrict__ x, const float* __restrict__ cb,
             const float* __restrict__ n2g, float* __restrict__ idxout,
             double* __restrict__ Rsum, double* __restrict__ minsum, int l) {
    __shared__ float Rch[64][33];   // 64 rows x 32 k, stride 33 -> conflict-free b32
    __shared__ int   jbuf[64][8];
    __shared__ float candV[4][64];
    __shared__ int   candI[4][64];
    __shared__ double redbuf[4];

    const int tid  = threadIdx.x;
    const int lane = tid & 63;
    const int wave = tid >> 6;
    const int row0 = blockIdx.x * 64;

    // stage previous-layer indices for this block's rows
    for (int i = tid; i < 64 * 8; i += 256) {
        int r = i >> 3, lp = i & 7;
        jbuf[r][lp] = (lp < l) ? (int)idxout[(size_t)(row0 + r) * LLAYERS + lp] : 0;
    }

    const int code0 = __builtin_amdgcn_readfirstlane(wave * 32);  // wave-uniform -> s_load path
    const float4* __restrict__ x4  = (const float4*)x;
    const float4* __restrict__ cb4 = (const float4*)cb;

    float acc[32];
    #pragma unroll
    for (int c = 0; c < 32; ++c) acc[c] = 0.f;

    float r2loc = 0.f;  // sum of r_l^2 over this thread's staged elements

    for (int kc = 0; kc < DDIM; kc += 32) {
        __syncthreads();
        // ---- stage residual chunk: r = x - sum_{lp<l} cb[lp][j_lp]  (same fp order as reference)
        #pragma unroll
        for (int i2 = 0; i2 < 2; ++i2) {
            int idx = tid + 256 * i2;      // 0..511 float4s = 64 rows x 8 f4
            int row = idx >> 3;
            int p   = idx & 7;
            float4 v = x4[(size_t)(row0 + row) * F4D + (kc >> 2) + p];
            for (int lp = 0; lp < l; ++lp) {
                int j = jbuf[row][lp];
                float4 cv = cb4[(size_t)(lp * KCODES + j) * F4D + (kc >> 2) + p];
                v.x -= cv.x; v.y -= cv.y; v.z -= cv.z; v.w -= cv.w;
            }
            r2loc = fmaf(v.x, v.x, r2loc); r2loc = fmaf(v.y, v.y, r2loc);
            r2loc = fmaf(v.z, v.z, r2loc); r2loc = fmaf(v.w, v.w, r2loc);
            float* dst = &Rch[row][p * 4];
            dst[0] = v.x; dst[1] = v.y; dst[2] = v.z; dst[3] = v.w;
        }
        __syncthreads();

        // ---- inner: lane = row, 32 codes per wave, codebook via scalar loads
        float rv[32];
        #pragma unroll
        for (int k = 0; k < 32; ++k) rv[k] = Rch[lane][k];

        const float* __restrict__ cpb = cb + ((size_t)(l * KCODES + code0) * DDIM) + kc;
        #pragma unroll
        for (int c = 0; c < 32; ++c) {
            const float* cp = cpb + c * DDIM;
            float s0 = 0.f, s1 = 0.f;  // 2 chains for ILP
            #pragma unroll
            for (int k = 0; k < 16; ++k) {
                s0 = fmaf(rv[2 * k],     cp[2 * k],     s0);
                s1 = fmaf(rv[2 * k + 1], cp[2 * k + 1], s1);
            }
            acc[c] += s0 + s1;
        }
    }

    // ---- scores + per-lane argmin (strict < ascending => numpy first-min)
    const float* n2p = n2g + l * KCODES + code0;
    float best = 3.4e38f; int bi = 0;
    #pragma unroll
    for (int c = 0; c < 32; ++c) {
        float sc = fmaf(-2.f, acc[c], n2p[c]);
        if (sc < best) { best = sc; bi = code0 + c; }
    }
    candV[wave][lane] = best; candI[wave][lane] = bi;
    __syncthreads();

    if (wave == 0) {
        float b = candV[0][lane]; int j = candI[0][lane];
        #pragma unroll
        for (int w = 1; w < 4; ++w) {   // ascending code groups, strict <
            float v = candV[w][lane];
            if (v < b) { b = v; j = candI[w][lane]; }
        }
        idxout[(size_t)(row0 + lane) * LLAYERS + l] = (float)j;
        double db = (double)b;
        for (int off = 32; off > 0; off >>= 1) db += __shfl_down(db, off);
        if (lane == 0) atomicAdd(&minsum[l], db);
    }

    // ---- block-reduce sum r_l^2 -> Rsum[l]
    double d = (double)r2loc;
    for (int off = 32; off > 0; off >>= 1) d += __shfl_down(d, off);
    if (lane == 0) redbuf[wave] = d;
    __syncthreads();
    if (tid == 0) atomicAdd(&Rsum[l], redbuf[0] + redbuf[1] + redbuf[2] + redbuf[3]);
}

__global__ __launch_bounds__(256)
void k_gather(const float* __restrict__ cb, const float* __restrict__ idxin,
              float* __restrict__ outq) {
    __shared__ int jb[32][8];
    int tid = threadIdx.x;
    int row0 = blockIdx.x * 32;
    {
        int r = tid >> 3, lp = tid & 7;
        jb[r][lp] = (int)idxin[(size_t)(row0 + r) * LLAYERS + lp];
    }
    __syncthreads();
    const float4* cb4 = (const float4*)cb;
    float4* out4 = (float4*)outq;
    for (int i = 0; i < 24; ++i) {
        int idx = tid + 256 * i;          // 0..6143 = 32 rows x 192 f4
        int row = idx / F4D;
        int p   = idx - row * F4D;
        float4 q; q.x = q.y = q.z = q.w = 0.f;
        #pragma unroll
        for (int l = 0; l < LLAYERS; ++l) {
            int j = jb[row][l];
            float4 c = cb4[(size_t)(l * KCODES + j) * F4D + p];
            q.x += c.x; q.y += c.y; q.z += c.z; q.w += c.w;
        }
        out4[(size_t)(row0 + row) * F4D + p] = q;
    }
}

__global__ void k_finalize(const double* __restrict__ Rsum, const double* __restrict__ minsum,
                           float* __restrict__ lossout) {
    int l = threadIdx.x;
    if (l < LLAYERS) {
        double s = (l < 7) ? Rsum[l + 1] : (Rsum[7] + minsum[7]);
        lossout[l] = (float)(0.25 * s / 50331648.0);
    }
}

extern "C" void kernel_launch(void* const* d_in, const int* in_sizes, int n_in,
                              void* d_out, int out_size, void* d_ws, size_t ws_size,
                              hipStream_t stream) {
    const float* x  = (const float*)d_in[0];
    const float* cb = (const float*)d_in[1];
    float* outq    = (float*)d_out;
    float* idxout  = (float*)d_out + (size_t)NROWS * DDIM;
    float* lossout = idxout + (size_t)NROWS * LLAYERS;

    double* Rsum   = (double*)d_ws;
    double* minsum = Rsum + 8;
    float*  n2     = (float*)((char*)d_ws + 128);

    hipMemsetAsync(d_ws, 0, 128, stream);
    k_norms<<<1024, 64, 0, stream>>>(cb, n2);
    for (int l = 0; l < LLAYERS; ++l)
        k_layer<<<NROWS / 64, 256, 0, stream>>>(x, cb, n2, idxout, Rsum, minsum, l);
    k_gather<<<NROWS / 32, 256, 0, stream>>>(cb, idxout, outq);
    k_finalize<<<1, 64, 0, stream>>>(Rsum, minsum, lossout);
}

// Round 2
// 2527.150 us; speedup vs baseline: 1.0014x; 1.0014x over previous
//
#include <hip/hip_runtime.h>

#define NROWS 65536
#define DDIM 768
#define KCODES 128
#define LLAYERS 8
#define F4D 192  // 768/4

// ws layout: bytes [0,64): double Rsum[8]; [64,128): double minsum[8]; [128,...): float n2[1024]

__global__ __launch_bounds__(64)
void k_norms(const float* __restrict__ cb, float* __restrict__ n2) {
    int c = blockIdx.x;  // 0..1023 = l*128+code
    const float* p = cb + (size_t)c * DDIM;
    int lane = threadIdx.x;
    float s = 0.f;
    for (int k = lane; k < DDIM; k += 64) s = fmaf(p[k], p[k], s);
    for (int off = 32; off > 0; off >>= 1) s += __shfl_down(s, off);
    if (lane == 0) n2[c] = s;
}

__global__ __launch_bounds__(256, 4)   // allow up to 128 VGPR: keep acc[32]+rv[32] resident
void k_layer(const float* __restrict__ x, const float* __restrict__ cb,
             const float* __restrict__ n2g, float* __restrict__ idxout,
             double* __restrict__ Rsum, double* __restrict__ minsum, int l) {
    __shared__ float Rch[64][36];   // stride 36 -> 16B-aligned rows, conflict-free b128
    __shared__ int   jbuf[64][8];
    __shared__ float candV[4][64];
    __shared__ int   candI[4][64];
    __shared__ double redbuf[4];

    const int tid  = threadIdx.x;
    const int lane = tid & 63;
    const int wave = tid >> 6;
    const int row0 = blockIdx.x * 64;

    // stage previous-layer indices for this block's rows
    for (int i = tid; i < 64 * 8; i += 256) {
        int r = i >> 3, lp = i & 7;
        jbuf[r][lp] = (lp < l) ? (int)idxout[(size_t)(row0 + r) * LLAYERS + lp] : 0;
    }

    const int code0 = __builtin_amdgcn_readfirstlane(wave * 32);  // wave-uniform -> s_load path
    const float4* __restrict__ x4  = (const float4*)x;
    const float4* __restrict__ cb4 = (const float4*)cb;

    float acc[32];
    #pragma unroll
    for (int c = 0; c < 32; ++c) acc[c] = 0.f;

    float r2loc = 0.f;  // sum of r_l^2 over this thread's staged elements

    for (int kc = 0; kc < DDIM; kc += 32) {
        __syncthreads();
        // ---- stage residual chunk: r = x - sum_{lp<l} cb[lp][j_lp]  (same fp order as reference)
        #pragma unroll
        for (int i2 = 0; i2 < 2; ++i2) {
            int idx = tid + 256 * i2;      // 0..511 float4s = 64 rows x 8 f4
            int row = idx >> 3;
            int p   = idx & 7;
            float4 v = x4[(size_t)(row0 + row) * F4D + (kc >> 2) + p];
            for (int lp = 0; lp < l; ++lp) {
                int j = jbuf[row][lp];
                float4 cv = cb4[(size_t)(lp * KCODES + j) * F4D + (kc >> 2) + p];
                v.x -= cv.x; v.y -= cv.y; v.z -= cv.z; v.w -= cv.w;
            }
            r2loc = fmaf(v.x, v.x, r2loc); r2loc = fmaf(v.y, v.y, r2loc);
            r2loc = fmaf(v.z, v.z, r2loc); r2loc = fmaf(v.w, v.w, r2loc);
            *(float4*)(&Rch[row][p * 4]) = v;
        }
        __syncthreads();

        // ---- load residual slice ONCE into registers (8 x ds_read_b128)
        float rv[32];
        #pragma unroll
        for (int q = 0; q < 8; ++q) {
            float4 t = *(const float4*)(&Rch[lane][4 * q]);
            rv[4 * q + 0] = t.x; rv[4 * q + 1] = t.y;
            rv[4 * q + 2] = t.z; rv[4 * q + 3] = t.w;
        }

        // ---- inner: lane = row, 32 codes per wave, codebook via scalar loads
        const float* __restrict__ cpb = cb + ((size_t)(l * KCODES + code0) * DDIM) + kc;
        #pragma unroll
        for (int c = 0; c < 32; ++c) {
            const float* cp = cpb + c * DDIM;
            float s0 = 0.f, s1 = 0.f, s2 = 0.f, s3 = 0.f;  // 4 chains for ILP
            #pragma unroll
            for (int k = 0; k < 8; ++k) {
                s0 = fmaf(rv[4 * k + 0], cp[4 * k + 0], s0);
                s1 = fmaf(rv[4 * k + 1], cp[4 * k + 1], s1);
                s2 = fmaf(rv[4 * k + 2], cp[4 * k + 2], s2);
                s3 = fmaf(rv[4 * k + 3], cp[4 * k + 3], s3);
            }
            acc[c] += (s0 + s1) + (s2 + s3);
        }
    }

    // ---- scores + per-lane argmin (strict < ascending => numpy first-min)
    const float* n2p = n2g + l * KCODES + code0;
    float best = 3.4e38f; int bi = 0;
    #pragma unroll
    for (int c = 0; c < 32; ++c) {
        float sc = fmaf(-2.f, acc[c], n2p[c]);
        if (sc < best) { best = sc; bi = code0 + c; }
    }
    candV[wave][lane] = best; candI[wave][lane] = bi;
    __syncthreads();

    if (wave == 0) {
        float b = candV[0][lane]; int j = candI[0][lane];
        #pragma unroll
        for (int w = 1; w < 4; ++w) {   // ascending code groups, strict <
            float v = candV[w][lane];
            if (v < b) { b = v; j = candI[w][lane]; }
        }
        idxout[(size_t)(row0 + lane) * LLAYERS + l] = (float)j;
        double db = (double)b;
        for (int off = 32; off > 0; off >>= 1) db += __shfl_down(db, off);
        if (lane == 0) atomicAdd(&minsum[l], db);
    }

    // ---- block-reduce sum r_l^2 -> Rsum[l]
    double d = (double)r2loc;
    for (int off = 32; off > 0; off >>= 1) d += __shfl_down(d, off);
    if (lane == 0) redbuf[wave] = d;
    __syncthreads();
    if (tid == 0) atomicAdd(&Rsum[l], redbuf[0] + redbuf[1] + redbuf[2] + redbuf[3]);
}

__global__ __launch_bounds__(256)
void k_gather(const float* __restrict__ cb, const float* __restrict__ idxin,
              float* __restrict__ outq) {
    __shared__ int jb[32][8];
    int tid = threadIdx.x;
    int row0 = blockIdx.x * 32;
    {
        int r = tid >> 3, lp = tid & 7;
        jb[r][lp] = (int)idxin[(size_t)(row0 + r) * LLAYERS + lp];
    }
    __syncthreads();
    const float4* cb4 = (const float4*)cb;
    float4* out4 = (float4*)outq;
    for (int i = 0; i < 24; ++i) {
        int idx = tid + 256 * i;          // 0..6143 = 32 rows x 192 f4
        int row = idx / F4D;
        int p   = idx - row * F4D;
        float4 q; q.x = q.y = q.z = q.w = 0.f;
        #pragma unroll
        for (int l = 0; l < LLAYERS; ++l) {
            int j = jb[row][l];
            float4 c = cb4[(size_t)(l * KCODES + j) * F4D + p];
            q.x += c.x; q.y += c.y; q.z += c.z; q.w += c.w;
        }
        out4[(size_t)(row0 + row) * F4D + p] = q;
    }
}

__global__ void k_finalize(const double* __restrict__ Rsum, const double* __restrict__ minsum,
                           float* __restrict__ lossout) {
    int l = threadIdx.x;
    if (l < LLAYERS) {
        double s = (l < 7) ? Rsum[l + 1] : (Rsum[7] + minsum[7]);
        lossout[l] = (float)(0.25 * s / 50331648.0);
    }
}

extern "C" void kernel_launch(void* const* d_in, const int* in_sizes, int n_in,
                              void* d_out, int out_size, void* d_ws, size_t ws_size,
                              hipStream_t stream) {
    const float* x  = (const float*)d_in[0];
    const float* cb = (const float*)d_in[1];
    float* outq    = (float*)d_out;
    float* idxout  = (float*)d_out + (size_t)NROWS * DDIM;
    float* lossout = idxout + (size_t)NROWS * LLAYERS;

    double* Rsum   = (double*)d_ws;
    double* minsum = Rsum + 8;
    float*  n2     = (float*)((char*)d_ws + 128);

    hipMemsetAsync(d_ws, 0, 128, stream);
    k_norms<<<1024, 64, 0, stream>>>(cb, n2);
    for (int l = 0; l < LLAYERS; ++l)
        k_layer<<<NROWS / 64, 256, 0, stream>>>(x, cb, n2, idxout, Rsum, minsum, l);
    k_gather<<<NROWS / 32, 256, 0, stream>>>(cb, idxout, outq);
    k_finalize<<<1, 64, 0, stream>>>(Rsum, minsum, lossout);
}